// Round 19
// baseline (52.793 us; speedup 1.0000x reference)
//
#include <hip/hip_runtime.h>

#define NPTS 262144
#define HID  20
#define NMID 8

typedef float f32x16 __attribute__((ext_vector_type(16)));
typedef _Float16 half8 __attribute__((ext_vector_type(8)));
typedef _Float16 h2 __attribute__((ext_vector_type(2)));
typedef __fp16 fp16x2 __attribute__((ext_vector_type(2)));
typedef unsigned int u32;

// RNE fp16 pair pack — value (H) stream only (bias discipline, R15 lesson).
__device__ __forceinline__ h2 pkh_rne(float a, float b) {
    h2 r; r.x = (_Float16)a; r.y = (_Float16)b;
    return r;
}
// RTZ fp16 pair pack (1 op) — derivative streams.
__device__ __forceinline__ h2 pkh_rtz(float a, float b) {
    fp16x2 r = __builtin_amdgcn_cvt_pkrtz(a, b);
    return __builtin_bit_cast(h2, r);
}
__device__ __forceinline__ u32 B(h2 v) { return __builtin_bit_cast(u32, v); }

__device__ __forceinline__ half8 mk_fragh(u32 a, u32 b, u32 c, u32 d) {
    uint4 v = make_uint4(a, b, c, d);
    return __builtin_bit_cast(half8, v);
}

#define MF2(A, Bo, C) __builtin_amdgcn_mfma_f32_32x32x16_f16(A, Bo, C, 0, 0, 0)

__launch_bounds__(256, 4)
__global__ void pde_mfma_kernel(const float* __restrict__ x,
                                const float* __restrict__ W_in,
                                const float* __restrict__ b_in,
                                const float* __restrict__ W_mid,
                                const float* __restrict__ b_mid,
                                const float* __restrict__ W_out,
                                const float* __restrict__ b_out,
                                float* __restrict__ out) {
    // fp16 A-frags, 3 parts/layer (24 KB): part0 = hi s=0; part1 = merged s=1
    // (lanes 0..31 hi, 32..63 lo); part2 = lo s=0. Lanes>=32 read s=1 frags from
    // a zero block (their A rows are zero). Weight k-columns permuted
    // (k -> k^12 for k in [4,12)) so B-frags equal local C/D register order.
    // H stream: hi+lo fp16 weights (21-bit eff). T/X/Q: hi only (11-bit).
    __shared__ short sWf[NMID * 3 * 64 * 8];   // 24 KB
    __shared__ float sIn[2 * 16 * 4];
    __shared__ short sZero[8];

    const int tid = threadIdx.x;

    for (int idx = tid; idx < NMID * 3 * 64 * 8 / 2; idx += 256)
        ((u32*)sWf)[idx] = 0u;
    if (tid < 4) ((u32*)sZero)[tid] = 0u;
    for (int idx = tid; idx < 32; idx += 256) {
        int h2i = idx >> 4, reg = idx & 15;
        int n = (reg & 3) + 8 * (reg >> 2) + 4 * h2i;
        float w0 = 0.f, w1 = 0.f, b = 0.f, wo = 0.f;
        if (n < HID) { w0 = W_in[n * 2]; w1 = W_in[n * 2 + 1]; b = b_in[n]; wo = W_out[n]; }
        sIn[idx * 4 + 0] = w0; sIn[idx * 4 + 1] = w1;
        sIn[idx * 4 + 2] = b;  sIn[idx * 4 + 3] = wo;
    }
    __syncthreads();
    for (int idx = tid; idx < NMID * HID * (HID + 1); idx += 256) {
        int layer = idx / (HID * (HID + 1));
        int rem   = idx % (HID * (HID + 1));
        int j = rem / (HID + 1);
        int k = rem % (HID + 1);
        float w = (k < HID) ? W_mid[(layer * HID + j) * HID + k] : b_mid[layer * HID + j];
        _Float16 whf = (_Float16)w;                       // RNE
        _Float16 wlf = (_Float16)(w - (float)whf);        // exact residual, RNE
        short whib = (short)__builtin_bit_cast(unsigned short, whf);
        short wlob = (short)__builtin_bit_cast(unsigned short, wlf);
        int kp = (k >= 4 && k < 12) ? (k ^ 12) : k;   // column permutation
        int s = kp >> 4, kk = kp & 15, hh = kk >> 3, r = kk & 7;
        int lane = j + 32 * hh;
        if (s == 0) {
            sWf[((layer * 3 + 0) * 64 + lane) * 8 + r] = whib;   // hi s0
            sWf[((layer * 3 + 2) * 64 + lane) * 8 + r] = wlob;   // lo s0
        } else {
            sWf[((layer * 3 + 1) * 64 + lane) * 8 + r]      = whib;  // hi s1
            sWf[((layer * 3 + 1) * 64 + lane + 32) * 8 + r] = wlob;  // lo s1
        }
    }
    __syncthreads();

    const int lane = tid & 63;
    const int wv   = tid >> 6;
    const int p    = lane & 31;
    const int hi   = lane >> 5;
    const int P    = blockIdx.x * 128 + wv * 32 + p;

    const float2 xv = reinterpret_cast<const float2*>(x)[P];
    const float x0 = xv.x, x1 = xv.y;
    const float bo = b_out[0];

    const float4* sIn4 = reinterpret_cast<const float4*>(sIn);

    float vh[12];                       // f32 value state (for output layer)
    h2 pka[6], pks[6], pkt[6], pkx[6], pkq[6];   // packed fp16 state

    // ---- input layer (fp32, exact; pack state) ----
    #pragma unroll
    for (int rr = 0; rr < 6; ++rr) {
        float aa[2], ss[2], tt[2], xx[2], qq[2];
        #pragma unroll
        for (int j2 = 0; j2 < 2; ++j2) {
            float4 t = sIn4[hi * 16 + 2 * rr + j2];
            float z = fmaf(t.x, x0, fmaf(t.y, x1, t.z));
            float e = __expf(z + z);
            float rc = __fdividef(1.0f, e + 1.0f);
            float a = fmaf(-2.0f, rc, 1.0f);
            float s = fmaf(-a, a, 1.0f);
            float sx = s * t.y;
            aa[j2] = a; ss[j2] = s; tt[j2] = s * t.x; xx[j2] = sx;
            qq[j2] = -2.0f * a * sx * t.y;
            vh[2 * rr + j2] = a;
        }
        pka[rr] = pkh_rne(aa[0], aa[1]);
        pks[rr] = pkh_rtz(ss[0], ss[1]);
        pkt[rr] = pkh_rtz(tt[0], tt[1]);
        pkx[rr] = pkh_rtz(xx[0], xx[1]);
        pkq[rr] = pkh_rtz(qq[0], qq[1]);
    }

    const f32x16 zz = 0.0f;
    const half8* afp = reinterpret_cast<const half8*>(sWf);
    const half8* pz  = reinterpret_cast<const half8*>(sZero);

    const half8* s1h = (lane < 32) ? (afp + 64 + lane)      : pz;
    const half8* s1l = (lane < 32) ? (afp + 64 + 32 + lane) : pz;
    const int s1stride = (lane < 32) ? 192 : 0;

    for (int layer = 0; layer < NMID; ++layer) {
        const int base = layer * 3 * 64;
        const half8 wh0 = afp[base + lane];
        const half8 wl0 = afp[base + 128 + lane];
        const half8 wh1 = s1h[layer * s1stride];
        const half8 wl1 = s1l[layer * s1stride];

        // ---- phase 1: B-frags are free bit_casts of packed state ----
        const half8 bH0 = mk_fragh(B(pka[0]), B(pka[1]), B(pka[2]), B(pka[3]));
        const half8 bH1 = mk_fragh(B(pka[4]), B(pka[5]), 0x00003C00u, 0u);
        const half8 bT0 = mk_fragh(B(pkt[0]), B(pkt[1]), B(pkt[2]), B(pkt[3]));
        const half8 bT1 = mk_fragh(B(pkt[4]), B(pkt[5]), 0u, 0u);
        const half8 bX0 = mk_fragh(B(pkx[0]), B(pkx[1]), B(pkx[2]), B(pkx[3]));
        const half8 bX1 = mk_fragh(B(pkx[4]), B(pkx[5]), 0u, 0u);
        const half8 bQ0 = mk_fragh(B(pkq[0]), B(pkq[1]), B(pkq[2]), B(pkq[3]));
        const half8 bQ1 = mk_fragh(B(pkq[4]), B(pkq[5]), 0u, 0u);

        f32x16 aH = MF2(wh0, bH0, zz);
        aH = MF2(wh1, bH1, aH);
        aH = MF2(wl0, bH0, aH);
        aH = MF2(wl1, bH1, aH);

        // ---- phase 2: tanh (f32) -> new a, s; repack ----
        #pragma unroll
        for (int rr = 0; rr < 6; ++rr) {
            float aa[2], ss[2];
            #pragma unroll
            for (int j2 = 0; j2 < 2; ++j2) {
                float z = aH[2 * rr + j2];
                float e = __expf(z + z);
                float rc = __fdividef(1.0f, e + 1.0f);
                float a = fmaf(-2.0f, rc, 1.0f);
                aa[j2] = a; ss[j2] = fmaf(-a, a, 1.0f);
                vh[2 * rr + j2] = a;
            }
            pka[rr] = pkh_rne(aa[0], aa[1]);
            pks[rr] = pkh_rtz(ss[0], ss[1]);
        }
        __builtin_amdgcn_sched_barrier(0);

        // ---- phase 3: T MFMAs + packed update ----
        f32x16 aT = MF2(wh0, bT0, zz);
        aT = MF2(wh1, bT1, aT);
        #pragma unroll
        for (int rr = 0; rr < 6; ++rr)
            pkt[rr] = pks[rr] * pkh_rtz(aT[2 * rr], aT[2 * rr + 1]);
        __builtin_amdgcn_sched_barrier(0);

        // ---- phase 4: X and Q MFMAs + packed pointwise ----
        f32x16 aX = MF2(wh0, bX0, zz);   f32x16 aQ = MF2(wh0, bQ0, zz);
        aX = MF2(wh1, bX1, aX);          aQ = MF2(wh1, bQ1, aQ);

        #pragma unroll
        for (int rr = 0; rr < 6; ++rr) {
            h2 zx = pkh_rtz(aX[2 * rr], aX[2 * rr + 1]);
            h2 zq = pkh_rtz(aQ[2 * rr], aQ[2 * rr + 1]);
            h2 nx = pks[rr] * zx;
            h2 u  = pka[rr] * nx;
            h2 t2 = u + u;
            pkx[rr] = nx;
            pkq[rr] = pks[rr] * zq - t2 * zx;
        }
    }

    // ---- output layer (unpack packed state once) ----
    float f = 0.f, ft = 0.f, fx = 0.f, fxx = 0.f;
    #pragma unroll
    for (int rr = 0; rr < 6; ++rr) {
        #pragma unroll
        for (int j2 = 0; j2 < 2; ++j2) {
            float w = sIn4[hi * 16 + 2 * rr + j2].w;
            f   = fmaf(w, vh[2 * rr + j2], f);
            ft  = fmaf(w, (float)(j2 ? pkt[rr].y : pkt[rr].x), ft);
            fx  = fmaf(w, (float)(j2 ? pkx[rr].y : pkx[rr].x), fx);
            fxx = fmaf(w, (float)(j2 ? pkq[rr].y : pkq[rr].x), fxx);
        }
    }
    f   += __shfl_xor(f, 32);
    ft  += __shfl_xor(ft, 32);
    fx  += __shfl_xor(fx, 32);
    fxx += __shfl_xor(fxx, 32);
    f += bo;

    if (!hi) {
        const float pde = 0.5f * x1 * x1 + ft + 0.5f * fxx + 0.5f * x1 * fx
                          - 0.069444444444444f * fx * fx;
        out[P] = f;
        out[NPTS + P] = pde;
    }
}

extern "C" void kernel_launch(void* const* d_in, const int* in_sizes, int n_in,
                              void* d_out, int out_size, void* d_ws, size_t ws_size,
                              hipStream_t stream) {
    const float* x     = (const float*)d_in[0];
    const float* W_in  = (const float*)d_in[1];
    const float* b_in  = (const float*)d_in[2];
    const float* W_mid = (const float*)d_in[3];
    const float* b_mid = (const float*)d_in[4];
    const float* W_out = (const float*)d_in[5];
    const float* b_out = (const float*)d_in[6];
    float* out = (float*)d_out;

    hipLaunchKernelGGL(pde_mfma_kernel, dim3(NPTS / 128), dim3(256), 0, stream,
                       x, W_in, b_in, W_mid, b_mid, W_out, b_out, out);
}

// Round 20
// 52.253 us; speedup vs baseline: 1.0103x; 1.0103x over previous
//
#include <hip/hip_runtime.h>

#define NPTS 262144
#define HID  20
#define NMID 8

typedef float f32x16 __attribute__((ext_vector_type(16)));
typedef float f32x2 __attribute__((ext_vector_type(2)));
typedef _Float16 half8 __attribute__((ext_vector_type(8)));
typedef __fp16 fp16x2 __attribute__((ext_vector_type(2)));
typedef unsigned int u32;

// RTZ fp16 pair pack (1 op, v_cvt_pkrtz_f16_f32) — all fragment packs.
__device__ __forceinline__ u32 pkh_rtz(float a, float b) {
    fp16x2 r = __builtin_amdgcn_cvt_pkrtz(a, b);
    return __builtin_bit_cast(u32, r);
}
__device__ __forceinline__ u32 pkh2(f32x2 v) { return pkh_rtz(v.x, v.y); }

__device__ __forceinline__ half8 mk_fragh(u32 a, u32 b, u32 c, u32 d) {
    uint4 v = make_uint4(a, b, c, d);
    return __builtin_bit_cast(half8, v);
}

#define MF2(A, Bo, C) __builtin_amdgcn_mfma_f32_32x32x16_f16(A, Bo, C, 0, 0, 0)

__launch_bounds__(256, 4)
__global__ void pde_mfma_kernel(const float* __restrict__ x,
                                const float* __restrict__ W_in,
                                const float* __restrict__ b_in,
                                const float* __restrict__ W_mid,
                                const float* __restrict__ b_mid,
                                const float* __restrict__ W_out,
                                const float* __restrict__ b_out,
                                float* __restrict__ out) {
    // fp16 A-frags, 3 parts/layer (24 KB): part0 = hi s=0; part1 = merged s=1
    // (lanes 0..31 hi, 32..63 lo); part2 = lo s=0. Lanes>=32 read s=1 frags from
    // a zero block (their A rows are zero). Weight k-columns permuted
    // (k -> k^12 for k in [4,12)) so B-frags equal local C/D register order.
    // H stream: hi+lo fp16 weights (21-bit eff). T/X/Q: hi only (11-bit).
    __shared__ short sWf[NMID * 3 * 64 * 8];   // 24 KB
    __shared__ float sIn[2 * 16 * 4];
    __shared__ short sZero[8];

    const int tid = threadIdx.x;

    for (int idx = tid; idx < NMID * 3 * 64 * 8 / 2; idx += 256)
        ((u32*)sWf)[idx] = 0u;
    if (tid < 4) ((u32*)sZero)[tid] = 0u;
    for (int idx = tid; idx < 32; idx += 256) {
        int hh = idx >> 4, reg = idx & 15;
        int n = (reg & 3) + 8 * (reg >> 2) + 4 * hh;
        float w0 = 0.f, w1 = 0.f, b = 0.f, wo = 0.f;
        if (n < HID) { w0 = W_in[n * 2]; w1 = W_in[n * 2 + 1]; b = b_in[n]; wo = W_out[n]; }
        sIn[idx * 4 + 0] = w0; sIn[idx * 4 + 1] = w1;
        sIn[idx * 4 + 2] = b;  sIn[idx * 4 + 3] = wo;
    }
    __syncthreads();
    for (int idx = tid; idx < NMID * HID * (HID + 1); idx += 256) {
        int layer = idx / (HID * (HID + 1));
        int rem   = idx % (HID * (HID + 1));
        int j = rem / (HID + 1);
        int k = rem % (HID + 1);
        float w = (k < HID) ? W_mid[(layer * HID + j) * HID + k] : b_mid[layer * HID + j];
        _Float16 whf = (_Float16)w;                       // RNE
        _Float16 wlf = (_Float16)(w - (float)whf);        // exact residual, RNE
        short whib = (short)__builtin_bit_cast(unsigned short, whf);
        short wlob = (short)__builtin_bit_cast(unsigned short, wlf);
        int kp = (k >= 4 && k < 12) ? (k ^ 12) : k;   // column permutation
        int s = kp >> 4, kk = kp & 15, hh = kk >> 3, r = kk & 7;
        int lane = j + 32 * hh;
        if (s == 0) {
            sWf[((layer * 3 + 0) * 64 + lane) * 8 + r] = whib;   // hi s0
            sWf[((layer * 3 + 2) * 64 + lane) * 8 + r] = wlob;   // lo s0
        } else {
            sWf[((layer * 3 + 1) * 64 + lane) * 8 + r]      = whib;  // hi s1
            sWf[((layer * 3 + 1) * 64 + lane + 32) * 8 + r] = wlob;  // lo s1
        }
    }
    __syncthreads();

    const int lane = tid & 63;
    const int wv   = tid >> 6;
    const int p    = lane & 31;
    const int hi   = lane >> 5;
    const int P    = blockIdx.x * 128 + wv * 32 + p;

    const float2 xv = reinterpret_cast<const float2*>(x)[P];
    const float x0 = xv.x, x1 = xv.y;
    const float bo = b_out[0];

    const float4* sIn4 = reinterpret_cast<const float4*>(sIn);

    // f32x2 state pairs — same precision as R18 scalars, pk-f32 pointwise.
    f32x2 vh[6], vs[6], vt[6], vx[6], vq[6];

    // ---- input layer (fp32, exact; scalar math, write pairs) ----
    #pragma unroll
    for (int rr = 0; rr < 6; ++rr) {
        #pragma unroll
        for (int j2 = 0; j2 < 2; ++j2) {
            float4 t = sIn4[hi * 16 + 2 * rr + j2];
            float z = fmaf(t.x, x0, fmaf(t.y, x1, t.z));
            float e = __expf(z + z);
            float rc = __fdividef(1.0f, e + 1.0f);
            float a = fmaf(-2.0f, rc, 1.0f);
            float s = fmaf(-a, a, 1.0f);
            float sx = s * t.y;
            vh[rr][j2] = a; vs[rr][j2] = s; vt[rr][j2] = s * t.x;
            vx[rr][j2] = sx; vq[rr][j2] = -2.0f * a * sx * t.y;
        }
    }

    const f32x16 zz = 0.0f;
    const half8* afp = reinterpret_cast<const half8*>(sWf);
    const half8* pz  = reinterpret_cast<const half8*>(sZero);

    const half8* s1h = (lane < 32) ? (afp + 64 + lane)      : pz;
    const half8* s1l = (lane < 32) ? (afp + 64 + 32 + lane) : pz;
    const int s1stride = (lane < 32) ? 192 : 0;

    for (int layer = 0; layer < NMID; ++layer) {
        const int base = layer * 3 * 64;
        const half8 wh0 = afp[base + lane];
        const half8 wl0 = afp[base + 128 + lane];
        const half8 wh1 = s1h[layer * s1stride];
        const half8 wl1 = s1l[layer * s1stride];

        // ---- phase 1: fragments (1-op RTZ packs) + H MFMAs ----
        const half8 bH0 = mk_fragh(pkh2(vh[0]), pkh2(vh[1]), pkh2(vh[2]), pkh2(vh[3]));
        const half8 bH1 = mk_fragh(pkh2(vh[4]), pkh2(vh[5]), 0x00003C00u, 0u);
        const half8 bT0 = mk_fragh(pkh2(vt[0]), pkh2(vt[1]), pkh2(vt[2]), pkh2(vt[3]));
        const half8 bT1 = mk_fragh(pkh2(vt[4]), pkh2(vt[5]), 0u, 0u);
        f32x16 aH = MF2(wh0, bH0, zz);
        aH = MF2(wh1, bH1, aH);
        aH = MF2(wl0, bH0, aH);
        aH = MF2(wl1, bH1, aH);

        // ---- phase 2: tanh (scalar f32) -> a; s via pk-fma ----
        #pragma unroll
        for (int rr = 0; rr < 6; ++rr) {
            #pragma unroll
            for (int j2 = 0; j2 < 2; ++j2) {
                float z = aH[2 * rr + j2];
                float e = __expf(z + z);
                float rc = __fdividef(1.0f, e + 1.0f);
                vh[rr][j2] = fmaf(-2.0f, rc, 1.0f);
            }
            vs[rr] = -(vh[rr] * vh[rr]) + 1.0f;   // v_pk_fma_f32
        }
        __builtin_amdgcn_sched_barrier(0);

        // ---- phase 3: T MFMAs + pk-f32 update ----
        f32x16 aT = MF2(wh0, bT0, zz);
        aT = MF2(wh1, bT1, aT);
        #pragma unroll
        for (int rr = 0; rr < 6; ++rr) {
            f32x2 zt; zt.x = aT[2 * rr]; zt.y = aT[2 * rr + 1];
            vt[rr] = vs[rr] * zt;                 // v_pk_mul_f32
        }

        const half8 bX0 = mk_fragh(pkh2(vx[0]), pkh2(vx[1]), pkh2(vx[2]), pkh2(vx[3]));
        const half8 bX1 = mk_fragh(pkh2(vx[4]), pkh2(vx[5]), 0u, 0u);
        const half8 bQ0 = mk_fragh(pkh2(vq[0]), pkh2(vq[1]), pkh2(vq[2]), pkh2(vq[3]));
        const half8 bQ1 = mk_fragh(pkh2(vq[4]), pkh2(vq[5]), 0u, 0u);
        __builtin_amdgcn_sched_barrier(0);

        // ---- phase 4: X and Q MFMAs + pk-f32 pointwise ----
        f32x16 aX = MF2(wh0, bX0, zz);   f32x16 aQ = MF2(wh0, bQ0, zz);
        aX = MF2(wh1, bX1, aX);          aQ = MF2(wh1, bQ1, aQ);

        #pragma unroll
        for (int rr = 0; rr < 6; ++rr) {
            f32x2 zx; zx.x = aX[2 * rr]; zx.y = aX[2 * rr + 1];
            f32x2 zq; zq.x = aQ[2 * rr]; zq.y = aQ[2 * rr + 1];
            f32x2 nx = vs[rr] * zx;               // pk_mul
            f32x2 u  = vh[rr] * nx;               // pk_mul
            f32x2 t2 = u + u;                     // pk_add
            vx[rr] = nx;
            vq[rr] = vs[rr] * zq - t2 * zx;       // pk_mul + pk_fma
        }
    }

    // ---- output layer ----
    float f = 0.f, ft = 0.f, fx = 0.f, fxx = 0.f;
    #pragma unroll
    for (int rr = 0; rr < 6; ++rr) {
        #pragma unroll
        for (int j2 = 0; j2 < 2; ++j2) {
            float w = sIn4[hi * 16 + 2 * rr + j2].w;
            f   = fmaf(w, vh[rr][j2], f);
            ft  = fmaf(w, vt[rr][j2], ft);
            fx  = fmaf(w, vx[rr][j2], fx);
            fxx = fmaf(w, vq[rr][j2], fxx);
        }
    }
    f   += __shfl_xor(f, 32);
    ft  += __shfl_xor(ft, 32);
    fx  += __shfl_xor(fx, 32);
    fxx += __shfl_xor(fxx, 32);
    f += bo;

    if (!hi) {
        const float pde = 0.5f * x1 * x1 + ft + 0.5f * fxx + 0.5f * x1 * fx
                          - 0.069444444444444f * fx * fx;
        out[P] = f;
        out[NPTS + P] = pde;
    }
}

extern "C" void kernel_launch(void* const* d_in, const int* in_sizes, int n_in,
                              void* d_out, int out_size, void* d_ws, size_t ws_size,
                              hipStream_t stream) {
    const float* x     = (const float*)d_in[0];
    const float* W_in  = (const float*)d_in[1];
    const float* b_in  = (const float*)d_in[2];
    const float* W_mid = (const float*)d_in[3];
    const float* b_mid = (const float*)d_in[4];
    const float* W_out = (const float*)d_in[5];
    const float* b_out = (const float*)d_in[6];
    float* out = (float*)d_out;

    hipLaunchKernelGGL(pde_mfma_kernel, dim3(NPTS / 128), dim3(256), 0, stream,
                       x, W_in, b_in, W_mid, b_mid, W_out, b_out, out);
}